// Round 1
// 854.529 us; speedup vs baseline: 1.2919x; 1.2919x over previous
//
#include <hip/hip_runtime.h>
#include <cstdint>

#define F_DIM 128
#define XSTR 136   // shorts per LDS row: 128 + 8 pad -> row stride 272 B, 2-way banks (free)

typedef short s16x8 __attribute__((ext_vector_type(8)));
typedef float f32x4 __attribute__((ext_vector_type(4)));

__device__ __forceinline__ uint32_t f2bf(float f){
    uint32_t u = __float_as_uint(f);
    return (u + 0x7FFFu + ((u >> 16) & 1u)) >> 16;   // RNE
}
__device__ __forceinline__ uint32_t packbf2(float lo, float hi){
    return f2bf(lo) | (f2bf(hi) << 16);
}
__device__ __forceinline__ uint2 cvt4(float4 v){
    return make_uint2(packbf2(v.x, v.y), packbf2(v.z, v.w));
}
// max(v,0) + log(1+exp(-|v|)) : v_exp_f32/v_log_f32 only, no log1pf libcall
__device__ __forceinline__ float softplus_f(float v){
    return fmaxf(v, 0.f) + __logf(1.f + __expf(-fabsf(v)));
}
__device__ __forceinline__ float silu_f(float v){
    return __fdividef(v, 1.f + __expf(-v));
}
// sum across the 16 lanes of a DPP row via rotate-reduce (all lanes get the sum).
// VALU-speed, no LDS pipe, no lgkm waits.
__device__ __forceinline__ float rowsum16(float p){
    p += __int_as_float(__builtin_amdgcn_update_dpp(0, __float_as_int(p), 0x121, 0xF, 0xF, false)); // row_ror:1
    p += __int_as_float(__builtin_amdgcn_update_dpp(0, __float_as_int(p), 0x122, 0xF, 0xF, false)); // row_ror:2
    p += __int_as_float(__builtin_amdgcn_update_dpp(0, __float_as_int(p), 0x124, 0xF, 0xF, false)); // row_ror:4
    p += __int_as_float(__builtin_amdgcn_update_dpp(0, __float_as_int(p), 0x128, 0xF, 0xF, false)); // row_ror:8
    return p;
}

// K0: zero pred/natom (2B floats at `zeroed`)
__global__ void k_prep(float* __restrict__ zeroed, int B){
    int gid = blockIdx.x*blockDim.x + threadIdx.x;
    if (gid < 2*B) zeroed[gid] = 0.f;
}

// K1: embed = softplus((|E[seg]|*Wk+bk) * (x@Wq+bq)) -> out; rowsums -> pred; counts -> natom
// 8 waves, wave w owns output cols [16w,16w+16); Wq strip in registers.
// kb table eliminated: Wk[col]/bk[col] hoisted, |E[seg[r]]| staged per-row in LDS.
__global__ void __launch_bounds__(512, 8) k_embed(
    const float* __restrict__ x, const int* __restrict__ seg,
    const float* __restrict__ Wq, const float* __restrict__ bq,
    const float* __restrict__ E, const float* __restrict__ Wk,
    const float* __restrict__ bk, float* __restrict__ out,
    float* __restrict__ pred, float* __restrict__ natom, int N)
{
    __shared__ __align__(16) short xs[128*XSTR];
    __shared__ __align__(16) float rs[128];
    __shared__ __align__(16) float es[128];
    __shared__ int ss[128];
    const int tid  = threadIdx.x;
    const int wave = tid >> 6, lane = tid & 63;
    const int quad = lane >> 4, ln = lane & 15;
    const int mycol = wave*16 + ln;

    // B fragments: B[k][n], n = lane&15, k = quad*8+j within each K=32 step
    s16x8 wf[4];
    #pragma unroll
    for (int s = 0; s < 4; ++s)
        #pragma unroll
        for (int j = 0; j < 8; ++j)
            wf[s][j] = (short)f2bf(Wq[(size_t)(s*32 + quad*8 + j)*F_DIM + mycol]);
    const float biasv = bq[mycol];
    const float wkv = Wk[mycol];
    const float bkv = bk[mycol];

    const int lrow = tid >> 5, lc4 = tid & 31;
    const int nt = (N + 127) >> 7;
    for (int tile = blockIdx.x; tile < nt; tile += gridDim.x){
        const int base = tile << 7;
        // stage seg / |E[seg]| per row; zero row-sum accumulators
        if (tid < 128){
            int r = base + tid;
            int sg = (r < N) ? seg[r] : 0;
            ss[tid] = sg;
            es[tid] = fabsf(E[sg]);
            rs[tid] = 0.f;
        }
        // stage x tile -> bf16 LDS (coalesced float4 reads, uint2 LDS writes)
        {
            const float4* xp = (const float4*)x + (size_t)(base + lrow)*32 + lc4;
            short* xsp = &xs[lrow*XSTR + lc4*4];
            #pragma unroll
            for (int j = 0; j < 8; ++j){
                if (base + lrow + j*16 < N)
                    *(uint2*)xsp = cvt4(*xp);
                xp  += 16*32;
                xsp += 16*XSTR;
            }
        }
        __syncthreads();

        float* orow = out + (size_t)(base + quad*4)*F_DIM + mycol;
        const short* arow = &xs[ln*XSTR + quad*8];
        #pragma unroll
        for (int rt = 0; rt < 8; ++rt){
            f32x4 acc = {0.f, 0.f, 0.f, 0.f};
            #pragma unroll
            for (int s = 0; s < 4; ++s){
                // A[m][k]: m = ln, k = quad*8+j  (16B-aligned ds_read_b128, imm offsets)
                s16x8 a = *(const s16x8*)(arow + rt*16*XSTR + s*32);
                acc = __builtin_amdgcn_mfma_f32_16x16x32_bf16(a, wf[s], acc, 0, 0, 0);
            }
            const int row0 = rt*16 + quad*4;
            f32x4 e4 = *(const f32x4*)&es[row0];   // one ds_read_b128, broadcast across ln
            #pragma unroll
            for (int reg = 0; reg < 4; ++reg){
                if (base + row0 + reg < N){          // uniform across the 16-lane DPP row
                    float kv = e4[reg]*wkv + bkv;
                    float e = softplus_f(kv * (acc[reg] + biasv));
                    orow[rt*16*F_DIM + reg*F_DIM] = e;
                    float p = rowsum16(e);
                    if (ln == 0) atomicAdd(&rs[row0 + reg], p);
                }
            }
        }
        __syncthreads();
        if (tid < 128 && base + tid < N){
            atomicAdd(&pred[ss[tid]], rs[tid]);
            atomicAdd(&natom[ss[tid]], 1.f);
        }
        __syncthreads();
    }
}

// K2: dsc[b] = (E[b]-pred[b])/natom[b]/F
__global__ void k_dsc(const float* __restrict__ E, const float* __restrict__ pred,
                      const float* __restrict__ natom, float* __restrict__ dsc, int B){
    int b = blockIdx.x*blockDim.x + threadIdx.x;
    if (b < B) dsc[b] = (E[b] - pred[b]) / natom[b] * (1.0f/128.0f);
}

// K3: se = embed + dsc[seg]; out = se + (silu(silu(se)@W1+b1)@W2+b2)  (in place on d_out)
// Single LDS buffer: GEMM1 output held bf16-packed in registers across a barrier,
// then scattered back into xs as t2.  LDS 35 KB -> 3 blocks/CU (was 2 with dual buffers).
__global__ void __launch_bounds__(512, 6) k_resid(
    const int* __restrict__ seg, const float* __restrict__ dsc,
    const float* __restrict__ W1, const float* __restrict__ b1,
    const float* __restrict__ W2, const float* __restrict__ b2,
    float* __restrict__ out, int N)
{
    __shared__ __align__(16) short xs[128*XSTR];
    __shared__ __align__(16) float dsl[128];
    const int tid  = threadIdx.x;
    const int wave = tid >> 6, lane = tid & 63;
    const int quad = lane >> 4, ln = lane & 15;
    const int mycol = wave*16 + ln;

    s16x8 w1f[4], w2f[4];
    #pragma unroll
    for (int s = 0; s < 4; ++s)
        #pragma unroll
        for (int j = 0; j < 8; ++j){
            int k = s*32 + quad*8 + j;
            w1f[s][j] = (short)f2bf(W1[(size_t)k*F_DIM + mycol]);
            w2f[s][j] = (short)f2bf(W2[(size_t)k*F_DIM + mycol]);
        }
    const float b1v = b1[mycol], b2v = b2[mycol];

    const int lrow = tid >> 5, lc4 = tid & 31;
    const int nt = (N + 127) >> 7;
    for (int tile = blockIdx.x; tile < nt; tile += gridDim.x){
        const int base = tile << 7;
        // stage t1 = silu(embed + dsc[seg]) -> bf16 LDS; stash dsc[seg[r]] per row
        {
            const float4* op = (const float4*)out + (size_t)(base + lrow)*32 + lc4;
            short* xsp = &xs[lrow*XSTR + lc4*4];
            #pragma unroll
            for (int j = 0; j < 8; ++j){
                int r = base + lrow + j*16;
                if (r < N){
                    float dv = dsc[seg[r]];
                    if (lc4 == 0) dsl[lrow + j*16] = dv;
                    float4 v = *op;
                    float4 t;
                    t.x = silu_f(v.x + dv); t.y = silu_f(v.y + dv);
                    t.z = silu_f(v.z + dv); t.w = silu_f(v.w + dv);
                    *(uint2*)xsp = cvt4(t);
                }
                op  += 16*32;
                xsp += 16*XSTR;
            }
        }
        __syncthreads();

        // GEMM1 + silu -> bf16-packed registers (16 VGPRs)
        uint32_t hp[16];
        const short* arow = &xs[ln*XSTR + quad*8];
        #pragma unroll
        for (int rt = 0; rt < 8; ++rt){
            f32x4 acc = {0.f, 0.f, 0.f, 0.f};
            #pragma unroll
            for (int s = 0; s < 4; ++s){
                s16x8 a = *(const s16x8*)(arow + rt*16*XSTR + s*32);
                acc = __builtin_amdgcn_mfma_f32_16x16x32_bf16(a, w1f[s], acc, 0, 0, 0);
            }
            hp[rt*2]   = packbf2(silu_f(acc[0]+b1v), silu_f(acc[1]+b1v));
            hp[rt*2+1] = packbf2(silu_f(acc[2]+b1v), silu_f(acc[3]+b1v));
        }
        __syncthreads();   // all GEMM1 reads of xs complete

        // scatter t2 = silu(h1) back into xs
        {
            short* tp = &xs[(quad*4)*XSTR + mycol];
            #pragma unroll
            for (int rt = 0; rt < 8; ++rt){
                tp[(rt*16+0)*XSTR] = (short)(hp[rt*2]   & 0xFFFFu);
                tp[(rt*16+1)*XSTR] = (short)(hp[rt*2]   >> 16);
                tp[(rt*16+2)*XSTR] = (short)(hp[rt*2+1] & 0xFFFFu);
                tp[(rt*16+3)*XSTR] = (short)(hp[rt*2+1] >> 16);
            }
        }
        __syncthreads();

        // GEMM2 + residual epilogue (re-read embed from global, L2-hot)
        float* orow = out + (size_t)(base + quad*4)*F_DIM + mycol;
        #pragma unroll
        for (int rt = 0; rt < 8; ++rt){
            f32x4 acc = {0.f, 0.f, 0.f, 0.f};
            #pragma unroll
            for (int s = 0; s < 4; ++s){
                s16x8 a = *(const s16x8*)(arow + rt*16*XSTR + s*32);
                acc = __builtin_amdgcn_mfma_f32_16x16x32_bf16(a, w2f[s], acc, 0, 0, 0);
            }
            const int row0 = rt*16 + quad*4;
            f32x4 d4 = *(const f32x4*)&dsl[row0];
            #pragma unroll
            for (int reg = 0; reg < 4; ++reg){
                if (base + row0 + reg < N){
                    float se = orow[rt*16*F_DIM + reg*F_DIM] + d4[reg];
                    orow[rt*16*F_DIM + reg*F_DIM] = se + acc[reg] + b2v;
                }
            }
        }
        __syncthreads();
    }
}

extern "C" void kernel_launch(void* const* d_in, const int* in_sizes, int n_in,
                              void* d_out, int out_size, void* d_ws, size_t ws_size,
                              hipStream_t stream)
{
    const float* x  = (const float*)d_in[0];
    const float* E  = (const float*)d_in[1];
    const int*  seg = (const int*)d_in[3];
    const float* Wq = (const float*)d_in[4];
    const float* bq = (const float*)d_in[5];
    const float* Wk = (const float*)d_in[6];
    const float* bk = (const float*)d_in[7];
    const float* W1 = (const float*)d_in[8];
    const float* b1 = (const float*)d_in[9];
    const float* W2 = (const float*)d_in[10];
    const float* b2 = (const float*)d_in[11];
    float* out = (float*)d_out;
    int N = in_sizes[0] / F_DIM;
    int B = in_sizes[1];

    float* pred  = (float*)d_ws;             // [B]
    float* natom = pred + B;                 // [B]
    float* dsc   = natom + B;                // [B]

    hipLaunchKernelGGL(k_prep, dim3((2*B + 255)/256), dim3(256), 0, stream,
                       pred, B);
    hipLaunchKernelGGL(k_embed, dim3(1024), dim3(512), 0, stream,
                       x, seg, Wq, bq, E, Wk, bk, out, pred, natom, N);
    hipLaunchKernelGGL(k_dsc, dim3((B + 255)/256), dim3(256), 0, stream,
                       E, pred, natom, dsc, B);
    hipLaunchKernelGGL(k_resid, dim3(768), dim3(512), 0, stream,
                       seg, dsc, W1, b1, W2, b2, out, N);
}

// Round 2
// 738.174 us; speedup vs baseline: 1.4955x; 1.1576x over previous
//
#include <hip/hip_runtime.h>
#include <cstdint>

#define F_DIM 128
#define XSTR 136   // shorts per LDS row: 128 + 8 pad -> row stride 272 B, 2-way banks (free)

typedef short s16x8 __attribute__((ext_vector_type(8)));
typedef float f32x4 __attribute__((ext_vector_type(4)));

__device__ __forceinline__ uint32_t f2bf(float f){
    uint32_t u = __float_as_uint(f);
    return (u + 0x7FFFu + ((u >> 16) & 1u)) >> 16;   // RNE
}
__device__ __forceinline__ uint32_t packbf2(float lo, float hi){
    return f2bf(lo) | (f2bf(hi) << 16);
}
__device__ __forceinline__ uint2 cvt4(float4 v){
    return make_uint2(packbf2(v.x, v.y), packbf2(v.z, v.w));
}
// max(v,0) + log(1+exp(-|v|)) : v_exp_f32/v_log_f32 only, no log1pf libcall
__device__ __forceinline__ float softplus_f(float v){
    return fmaxf(v, 0.f) + __logf(1.f + __expf(-fabsf(v)));
}
__device__ __forceinline__ float silu_f(float v){
    return __fdividef(v, 1.f + __expf(-v));
}
// sum across the 16 lanes of a DPP row via rotate-reduce (all lanes get the sum).
__device__ __forceinline__ float rowsum16(float p){
    p += __int_as_float(__builtin_amdgcn_update_dpp(0, __float_as_int(p), 0x121, 0xF, 0xF, false)); // row_ror:1
    p += __int_as_float(__builtin_amdgcn_update_dpp(0, __float_as_int(p), 0x122, 0xF, 0xF, false)); // row_ror:2
    p += __int_as_float(__builtin_amdgcn_update_dpp(0, __float_as_int(p), 0x124, 0xF, 0xF, false)); // row_ror:4
    p += __int_as_float(__builtin_amdgcn_update_dpp(0, __float_as_int(p), 0x128, 0xF, 0xF, false)); // row_ror:8
    return p;
}

// K0: zero pred/natom
__global__ void k_prep(float* __restrict__ zeroed, int B){
    int gid = blockIdx.x*blockDim.x + threadIdx.x;
    if (gid < 2*B) zeroed[gid] = 0.f;
}

// K1 (k_sum): rowsum(softplus((|E[seg]|*Wk+bk)*(x@Wq+bq))) -> pred; counts -> natom.
// NO embed store.  Full-tile fast path stages 8 float4 loads in flight.
__global__ void __launch_bounds__(512, 8) k_sum(
    const float* __restrict__ x, const int* __restrict__ seg,
    const float* __restrict__ Wq, const float* __restrict__ bq,
    const float* __restrict__ E, const float* __restrict__ Wk,
    const float* __restrict__ bk,
    float* __restrict__ pred, float* __restrict__ natom, int N)
{
    __shared__ __align__(16) short xs[128*XSTR];
    __shared__ __align__(16) float rs[128];
    __shared__ __align__(16) float es[128];
    __shared__ int ss[128];
    const int tid  = threadIdx.x;
    const int wave = tid >> 6, lane = tid & 63;
    const int quad = lane >> 4, ln = lane & 15;
    const int mycol = wave*16 + ln;

    s16x8 wf[4];
    #pragma unroll
    for (int s = 0; s < 4; ++s)
        #pragma unroll
        for (int j = 0; j < 8; ++j)
            wf[s][j] = (short)f2bf(Wq[(size_t)(s*32 + quad*8 + j)*F_DIM + mycol]);
    const float biasv = bq[mycol];
    const float wkv = Wk[mycol];
    const float bkv = bk[mycol];

    const int lrow = tid >> 5, lc4 = tid & 31;
    const int nt = (N + 127) >> 7;
    for (int tile = blockIdx.x; tile < nt; tile += gridDim.x){
        const int base = tile << 7;
        const bool full = (base + 128 <= N);
        if (tid < 128){
            int r = base + tid;
            int sg = (r < N) ? seg[r] : 0;
            ss[tid] = sg;
            es[tid] = fabsf(E[sg]);
            rs[tid] = 0.f;
        }
        {
            const float4* xp = (const float4*)x + (size_t)(base + lrow)*32 + lc4;
            short* xsp = &xs[lrow*XSTR + lc4*4];
            if (full){
                float4 v0 = xp[0*512], v1 = xp[1*512], v2 = xp[2*512], v3 = xp[3*512];
                float4 v4 = xp[4*512], v5 = xp[5*512], v6 = xp[6*512], v7 = xp[7*512];
                *(uint2*)&xsp[0*16*XSTR] = cvt4(v0);
                *(uint2*)&xsp[1*16*XSTR] = cvt4(v1);
                *(uint2*)&xsp[2*16*XSTR] = cvt4(v2);
                *(uint2*)&xsp[3*16*XSTR] = cvt4(v3);
                *(uint2*)&xsp[4*16*XSTR] = cvt4(v4);
                *(uint2*)&xsp[5*16*XSTR] = cvt4(v5);
                *(uint2*)&xsp[6*16*XSTR] = cvt4(v6);
                *(uint2*)&xsp[7*16*XSTR] = cvt4(v7);
            } else {
                #pragma unroll
                for (int j = 0; j < 8; ++j){
                    if (base + lrow + j*16 < N) *(uint2*)&xsp[j*16*XSTR] = cvt4(xp[j*512]);
                    else                        *(uint2*)&xsp[j*16*XSTR] = make_uint2(0u, 0u);
                }
            }
        }
        __syncthreads();

        const short* arow = &xs[ln*XSTR + quad*8];
        #pragma unroll
        for (int rt = 0; rt < 8; ++rt){
            f32x4 acc = {0.f, 0.f, 0.f, 0.f};
            #pragma unroll
            for (int s = 0; s < 4; ++s){
                s16x8 a = *(const s16x8*)(arow + rt*16*XSTR + s*32);
                acc = __builtin_amdgcn_mfma_f32_16x16x32_bf16(a, wf[s], acc, 0, 0, 0);
            }
            const int row0 = rt*16 + quad*4;
            f32x4 e4 = *(const f32x4*)&es[row0];
            #pragma unroll
            for (int reg = 0; reg < 4; ++reg){
                if (full || base + row0 + reg < N){
                    float kv = e4[reg]*wkv + bkv;
                    float e = softplus_f(kv * (acc[reg] + biasv));
                    float p = rowsum16(e);
                    if (ln == 0) atomicAdd(&rs[row0 + reg], p);
                }
            }
        }
        __syncthreads();
        if (tid < 128 && base + tid < N){
            atomicAdd(&pred[ss[tid]], rs[tid]);
            atomicAdd(&natom[ss[tid]], 1.f);
        }
        __syncthreads();
    }
}

// K2: dsc[b] = (E[b]-pred[b])/natom[b]/F
__global__ void k_dsc(const float* __restrict__ E, const float* __restrict__ pred,
                      const float* __restrict__ natom, float* __restrict__ dsc, int B){
    int b = blockIdx.x*blockDim.x + threadIdx.x;
    if (b < B) dsc[b] = (E[b] - pred[b]) / natom[b] * (1.0f/128.0f);
}

// K3 (k_main): recompute q-GEMM -> embed (bitwise same as k_sum's), se = embed + dsc[seg]
// kept in 32 f32 VGPRs, then t1=silu(se)@W1 -> silu -> @W2, out = se + h2 + b2.
// out is write-only.  Single LDS buffer reused for x-tile / t1 / t2.
__global__ void __launch_bounds__(512, 4) k_main(
    const float* __restrict__ x, const int* __restrict__ seg,
    const float* __restrict__ Wq, const float* __restrict__ bq,
    const float* __restrict__ E, const float* __restrict__ Wk,
    const float* __restrict__ bk, const float* __restrict__ dsc,
    const float* __restrict__ W1, const float* __restrict__ b1,
    const float* __restrict__ W2, const float* __restrict__ b2,
    float* __restrict__ out, int N)
{
    __shared__ __align__(16) short xs[128*XSTR];
    __shared__ __align__(16) float es[128];
    __shared__ __align__(16) float dsl[128];
    const int tid  = threadIdx.x;
    const int wave = tid >> 6, lane = tid & 63;
    const int quad = lane >> 4, ln = lane & 15;
    const int mycol = wave*16 + ln;

    s16x8 wqf[4], w1f[4], w2f[4];
    #pragma unroll
    for (int s = 0; s < 4; ++s)
        #pragma unroll
        for (int j = 0; j < 8; ++j){
            int k = s*32 + quad*8 + j;
            wqf[s][j] = (short)f2bf(Wq[(size_t)k*F_DIM + mycol]);
            w1f[s][j] = (short)f2bf(W1[(size_t)k*F_DIM + mycol]);
            w2f[s][j] = (short)f2bf(W2[(size_t)k*F_DIM + mycol]);
        }
    const float biasv = bq[mycol];
    const float wkv = Wk[mycol];
    const float bkv = bk[mycol];
    const float b1v = b1[mycol], b2v = b2[mycol];

    const int lrow = tid >> 5, lc4 = tid & 31;
    const int nt = (N + 127) >> 7;
    for (int tile = blockIdx.x; tile < nt; tile += gridDim.x){
        const int base = tile << 7;
        const bool full = (base + 128 <= N);
        if (tid < 128){
            int r = base + tid;
            int sg = (r < N) ? seg[r] : 0;
            es[tid]  = fabsf(E[sg]);
            dsl[tid] = dsc[sg];
        }
        // stage x -> bf16 LDS, loads batched in flight on the fast path
        {
            const float4* xp = (const float4*)x + (size_t)(base + lrow)*32 + lc4;
            short* xsp = &xs[lrow*XSTR + lc4*4];
            if (full){
                float4 v0 = xp[0*512], v1 = xp[1*512], v2 = xp[2*512], v3 = xp[3*512];
                float4 v4 = xp[4*512], v5 = xp[5*512], v6 = xp[6*512], v7 = xp[7*512];
                *(uint2*)&xsp[0*16*XSTR] = cvt4(v0);
                *(uint2*)&xsp[1*16*XSTR] = cvt4(v1);
                *(uint2*)&xsp[2*16*XSTR] = cvt4(v2);
                *(uint2*)&xsp[3*16*XSTR] = cvt4(v3);
                *(uint2*)&xsp[4*16*XSTR] = cvt4(v4);
                *(uint2*)&xsp[5*16*XSTR] = cvt4(v5);
                *(uint2*)&xsp[6*16*XSTR] = cvt4(v6);
                *(uint2*)&xsp[7*16*XSTR] = cvt4(v7);
            } else {
                #pragma unroll
                for (int j = 0; j < 8; ++j){
                    if (base + lrow + j*16 < N) *(uint2*)&xsp[j*16*XSTR] = cvt4(xp[j*512]);
                    else                        *(uint2*)&xsp[j*16*XSTR] = make_uint2(0u, 0u);
                }
            }
        }
        __syncthreads();

        // GEMM-q -> embed -> se (32 f32 regs, bitwise same embed as k_sum)
        float se[32];
        const short* arow = &xs[ln*XSTR + quad*8];
        #pragma unroll
        for (int rt = 0; rt < 8; ++rt){
            f32x4 acc = {0.f, 0.f, 0.f, 0.f};
            #pragma unroll
            for (int s = 0; s < 4; ++s){
                s16x8 a = *(const s16x8*)(arow + rt*16*XSTR + s*32);
                acc = __builtin_amdgcn_mfma_f32_16x16x32_bf16(a, wqf[s], acc, 0, 0, 0);
            }
            const int row0 = rt*16 + quad*4;
            f32x4 e4 = *(const f32x4*)&es[row0];
            f32x4 d4 = *(const f32x4*)&dsl[row0];
            #pragma unroll
            for (int reg = 0; reg < 4; ++reg){
                float kv = e4[reg]*wkv + bkv;
                float e = softplus_f(kv * (acc[reg] + biasv));
                se[rt*4 + reg] = e + d4[reg];
            }
        }
        __syncthreads();   // all GEMM-q reads of xs done

        // scatter t1 = silu(se) -> xs
        {
            short* tp = &xs[(quad*4)*XSTR + mycol];
            #pragma unroll
            for (int rt = 0; rt < 8; ++rt)
                #pragma unroll
                for (int r = 0; r < 4; ++r)
                    tp[(rt*16 + r)*XSTR] = (short)f2bf(silu_f(se[rt*4 + r]));
        }
        __syncthreads();

        // GEMM1 + silu -> bf16-packed regs
        uint32_t hp[16];
        #pragma unroll
        for (int rt = 0; rt < 8; ++rt){
            f32x4 acc = {0.f, 0.f, 0.f, 0.f};
            #pragma unroll
            for (int s = 0; s < 4; ++s){
                s16x8 a = *(const s16x8*)(arow + rt*16*XSTR + s*32);
                acc = __builtin_amdgcn_mfma_f32_16x16x32_bf16(a, w1f[s], acc, 0, 0, 0);
            }
            hp[rt*2]   = packbf2(silu_f(acc[0]+b1v), silu_f(acc[1]+b1v));
            hp[rt*2+1] = packbf2(silu_f(acc[2]+b1v), silu_f(acc[3]+b1v));
        }
        __syncthreads();

        // scatter t2 -> xs
        {
            short* tp = &xs[(quad*4)*XSTR + mycol];
            #pragma unroll
            for (int rt = 0; rt < 8; ++rt){
                tp[(rt*16+0)*XSTR] = (short)(hp[rt*2]   & 0xFFFFu);
                tp[(rt*16+1)*XSTR] = (short)(hp[rt*2]   >> 16);
                tp[(rt*16+2)*XSTR] = (short)(hp[rt*2+1] & 0xFFFFu);
                tp[(rt*16+3)*XSTR] = (short)(hp[rt*2+1] >> 16);
            }
        }
        __syncthreads();

        // GEMM2 + epilogue: out = se + h2 + b2 (pure write)
        float* orow = out + (size_t)(base + quad*4)*F_DIM + mycol;
        #pragma unroll
        for (int rt = 0; rt < 8; ++rt){
            f32x4 acc = {0.f, 0.f, 0.f, 0.f};
            #pragma unroll
            for (int s = 0; s < 4; ++s){
                s16x8 a = *(const s16x8*)(arow + rt*16*XSTR + s*32);
                acc = __builtin_amdgcn_mfma_f32_16x16x32_bf16(a, w2f[s], acc, 0, 0, 0);
            }
            const int row0 = rt*16 + quad*4;
            #pragma unroll
            for (int reg = 0; reg < 4; ++reg){
                if (full || base + row0 + reg < N)
                    orow[rt*16*F_DIM + reg*F_DIM] = se[rt*4+reg] + acc[reg] + b2v;
            }
        }
        __syncthreads();
    }
}

extern "C" void kernel_launch(void* const* d_in, const int* in_sizes, int n_in,
                              void* d_out, int out_size, void* d_ws, size_t ws_size,
                              hipStream_t stream)
{
    const float* x  = (const float*)d_in[0];
    const float* E  = (const float*)d_in[1];
    const int*  seg = (const int*)d_in[3];
    const float* Wq = (const float*)d_in[4];
    const float* bq = (const float*)d_in[5];
    const float* Wk = (const float*)d_in[6];
    const float* bk = (const float*)d_in[7];
    const float* W1 = (const float*)d_in[8];
    const float* b1 = (const float*)d_in[9];
    const float* W2 = (const float*)d_in[10];
    const float* b2 = (const float*)d_in[11];
    float* out = (float*)d_out;
    int N = in_sizes[0] / F_DIM;
    int B = in_sizes[1];

    float* pred  = (float*)d_ws;             // [B]
    float* natom = pred + B;                 // [B]
    float* dsc   = natom + B;                // [B]

    hipLaunchKernelGGL(k_prep, dim3((2*B + 255)/256), dim3(256), 0, stream,
                       pred, B);
    hipLaunchKernelGGL(k_sum, dim3(1024), dim3(512), 0, stream,
                       x, seg, Wq, bq, E, Wk, bk, pred, natom, N);
    hipLaunchKernelGGL(k_dsc, dim3((B + 255)/256), dim3(256), 0, stream,
                       E, pred, natom, dsc, B);
    hipLaunchKernelGGL(k_main, dim3(512), dim3(512), 0, stream,
                       x, seg, Wq, bq, E, Wk, bk, dsc, W1, b1, W2, b2, out, N);
}